// Round 7
// baseline (139.976 us; speedup 1.0000x reference)
//
#include <hip/hip_runtime.h>

// (B,N,F,K) = (4096, 2048, 64, 64)
#define NB 4096
#define NN 2048
#define NF 64
#define NK 64

#define RPB   16              // rows per block
#define TPB   1024            // 16 waves
#define NWAVE 16
#define CPW   (NN / NWAVE)    // 128 contraction cols per wave
#define KS    (CPW / 32)      // 4 MFMA K-steps per wave
#define GRID  (NB / RPB)      // 256 blocks

typedef short bf16x8 __attribute__((ext_vector_type(8)));
typedef float f32x4  __attribute__((ext_vector_type(4)));

// ws byte offsets (256B aligned)
#define OFF_VGTH 0                          // ushort [64][2048] hi
#define OFF_VGTL (OFF_VGTH + NK * NN * 2)   // ushort [64][2048] lo
#define OFF_VN   (OFF_VGTL + NK * NN * 2)   // float  [2048]
#define OFF_LINT (OFF_VN + NN * 4)          // float  [4096]
#define OFF_STOT (OFF_LINT + NB * 4)        // float  [1]

__device__ inline unsigned short bf16_rtn(float f) {
    unsigned u = __float_as_uint(f);
    return (unsigned short)((u + 0x7fffu + ((u >> 16) & 1u)) >> 16);
}

// ---------- k_prep: gather V rows, bf16 hi/lo split, store transposed [k][i]; arm stot ----------
__global__ __launch_bounds__(256) void k_prep(const float* __restrict__ vec,
                                              const int* __restrict__ f2f,
                                              unsigned short* __restrict__ VgTh,
                                              unsigned short* __restrict__ VgTl,
                                              float* __restrict__ vnorm,
                                              float* __restrict__ stot) {
    __shared__ unsigned short tH[64][72];
    __shared__ unsigned short tL[64][72];
    const int t  = threadIdx.x;
    const int i0 = blockIdx.x * 64;
    if (blockIdx.x == 0 && t == 0) *stot = 0.f;   // re-arm accumulator every launch
    {
        const int il = t >> 2;
        const int sg = (t & 3) * 16;
        const int i  = i0 + il;
        const int f  = f2f[i];
        const float* p = vec + (size_t)i * (NF * NK) + (size_t)f * NK + sg;
        float nsum = 0.f;
        #pragma unroll
        for (int j4 = 0; j4 < 4; ++j4) {
            float4 v = *reinterpret_cast<const float4*>(p + j4 * 4);
            float vv[4] = {v.x, v.y, v.z, v.w};
            #pragma unroll
            for (int e = 0; e < 4; ++e) {
                float x = vv[e];
                nsum = fmaf(x, x, nsum);
                unsigned xb = __float_as_uint(x);
                float hf = __uint_as_float(xb & 0xffff0000u);
                int k = sg + j4 * 4 + e;
                tH[il][k] = (unsigned short)(xb >> 16);
                tL[il][k] = bf16_rtn(x - hf);
            }
        }
        nsum += __shfl_xor(nsum, 1, 64);
        nsum += __shfl_xor(nsum, 2, 64);
        if ((t & 3) == 0) vnorm[i] = nsum;   // vnorm from EXACT fp32 values
    }
    __syncthreads();
    {
        const int k  = t >> 2;
        const int is = (t & 3) * 16;
        unsigned short hb[16], lb[16];
        #pragma unroll
        for (int j = 0; j < 16; ++j) { hb[j] = tH[is + j][k]; lb[j] = tL[is + j][k]; }
        unsigned short* ph = VgTh + (size_t)k * NN + i0 + is;
        unsigned short* pl = VgTl + (size_t)k * NN + i0 + is;
        *reinterpret_cast<uint4*>(ph)     = *reinterpret_cast<uint4*>(hb);
        *reinterpret_cast<uint4*>(ph + 8) = *reinterpret_cast<uint4*>(hb + 8);
        *reinterpret_cast<uint4*>(pl)     = *reinterpret_cast<uint4*>(lb);
        *reinterpret_cast<uint4*>(pl + 8) = *reinterpret_cast<uint4*>(lb + 8);
    }
}

// ---------- k_main: full-contraction MFMA + cross-wave reduce + one atomic/block ----------
// block = 16 rows x 2048 cols; wave w owns cols [128w,128w+128); 2 blocks/CU.
__global__ __launch_bounds__(TPB, 8) void k_main(const float* __restrict__ X,
                                                 const float* __restrict__ Wg,
                                                 const unsigned short* __restrict__ VgTh,
                                                 const unsigned short* __restrict__ VgTl,
                                                 const float* __restrict__ vn,
                                                 float* __restrict__ lint,
                                                 float* __restrict__ stot) {
    __shared__ float Tl[NWAVE * 1088];   // [w][row(stride 68)][lat]: 68 KB, all <=2-way
    __shared__ float linW[NWAVE * 17];
    __shared__ float ddW[NWAVE * 17];
    __shared__ float rowRes[RPB];

    const int t    = threadIdx.x;
    const int w    = t >> 6;          // wave = contraction slice
    const int lane = t & 63;
    const int m    = lane & 15;
    const int quad = lane >> 4;
    const int r0   = blockIdx.x * RPB;
    const int row  = r0 + m;
    const int cw   = w * CPW;

    const float* xp = X  + (size_t)row * NN + cw + quad * 8;
    const float* wp = Wg + cw + quad * 8;
    const float* np = vn + cw + quad * 8;
    const unsigned short* bhp = VgTh + (size_t)m * NN + cw + quad * 8;
    const unsigned short* blp = VgTl + (size_t)m * NN + cw + quad * 8;

    f32x4 acc[4];
    #pragma unroll
    for (int nt = 0; nt < 4; ++nt)
        #pragma unroll
        for (int e = 0; e < 4; ++e) acc[nt][e] = 0.f;
    float lin = 0.f, dd = 0.f;

    #pragma unroll
    for (int s = 0; s < KS; ++s) {
        float4 xa = *reinterpret_cast<const float4*>(xp + s * 32);
        float4 xb = *reinterpret_cast<const float4*>(xp + s * 32 + 4);
        float4 wa = *reinterpret_cast<const float4*>(wp + s * 32);
        float4 wb = *reinterpret_cast<const float4*>(wp + s * 32 + 4);
        float4 na = *reinterpret_cast<const float4*>(np + s * 32);
        float4 nb = *reinterpret_cast<const float4*>(np + s * 32 + 4);

        float xs8[8] = {xa.x, xa.y, xa.z, xa.w, xb.x, xb.y, xb.z, xb.w};
        float ws8[8] = {wa.x, wa.y, wa.z, wa.w, wb.x, wb.y, wb.z, wb.w};
        float ns8[8] = {na.x, na.y, na.z, na.w, nb.x, nb.y, nb.z, nb.w};

        #pragma unroll
        for (int j = 0; j < 8; ++j) {
            lin = fmaf(xs8[j], ws8[j], lin);
            dd  = fmaf(xs8[j] * xs8[j], ns8[j], dd);
        }

        bf16x8 ah, al;
        #pragma unroll
        for (int j = 0; j < 8; ++j) {
            unsigned ub = __float_as_uint(xs8[j]);
            ah[j] = (short)(ub >> 16);
            float hf = __uint_as_float(ub & 0xffff0000u);
            al[j] = (short)bf16_rtn(xs8[j] - hf);
        }

        #pragma unroll
        for (int nt = 0; nt < 4; ++nt) {
            bf16x8 bh = *reinterpret_cast<const bf16x8*>(bhp + (size_t)nt * 16 * NN + s * 32);
            bf16x8 bl = *reinterpret_cast<const bf16x8*>(blp + (size_t)nt * 16 * NN + s * 32);
            acc[nt] = __builtin_amdgcn_mfma_f32_16x16x32_bf16(ah, bh, acc[nt], 0, 0, 0);
            acc[nt] = __builtin_amdgcn_mfma_f32_16x16x32_bf16(al, bh, acc[nt], 0, 0, 0);
            acc[nt] = __builtin_amdgcn_mfma_f32_16x16x32_bf16(ah, bl, acc[nt], 0, 0, 0);
        }
    }

    // ---- stash wave-partial T tile: C-layout row=quad*4+r, col=nt*16+m ----
    #pragma unroll
    for (int nt = 0; nt < 4; ++nt)
        #pragma unroll
        for (int r = 0; r < 4; ++r)
            Tl[w * 1088 + (quad * 4 + r) * 68 + nt * 16 + m] = acc[nt][r];

    lin += __shfl_xor(lin, 16, 64); lin += __shfl_xor(lin, 32, 64);
    dd  += __shfl_xor(dd, 16, 64);  dd  += __shfl_xor(dd, 32, 64);
    if (quad == 0) { linW[w * 17 + m] = lin; ddW[w * 17 + m] = dd; }
    __syncthreads();

    // ---- per-row phase: wave w owns row w; lane = latent k ----
    {
        float ts = 0.f;
        #pragma unroll
        for (int ww = 0; ww < NWAVE; ++ww)
            ts += Tl[ww * 1088 + w * 68 + lane];
        float s2 = ts * ts;
        #pragma unroll
        for (int d = 1; d < 64; d <<= 1) s2 += __shfl_xor(s2, d, 64);
        float lw = (lane < 16) ? linW[lane * 17 + w] : 0.f;
        float dw = (lane < 16) ? ddW [lane * 17 + w] : 0.f;
        #pragma unroll
        for (int d = 1; d < 16; d <<= 1) {
            lw += __shfl_xor(lw, d, 64);
            dw += __shfl_xor(dw, d, 64);
        }
        if (lane == 0) {
            lint[r0 + w] = lw;          // per-row linear part
            rowRes[w]    = s2 - dw;     // per-row interaction partial
        }
    }
    __syncthreads();

    if (t == 0) {
        float p = 0.f;
        #pragma unroll
        for (int r = 0; r < RPB; ++r) p += rowRes[r];
        atomicAdd(stot, p);             // device-scope, no fences needed
    }
}

// ---------- k_final: broadcast ----------
__global__ __launch_bounds__(256) void k_final(const float* __restrict__ lint,
                                               const float* __restrict__ stot,
                                               const float* __restrict__ bptr,
                                               float* __restrict__ out) {
    int b = blockIdx.x * 256 + threadIdx.x;
    out[b] = lint[b] + bptr[0] + 0.5f * stot[0];
}

extern "C" void kernel_launch(void* const* d_in, const int* in_sizes, int n_in,
                              void* d_out, int out_size, void* d_ws, size_t ws_size,
                              hipStream_t stream) {
    const float* X    = (const float*)d_in[0];
    const float* W    = (const float*)d_in[1];
    const float* bias = (const float*)d_in[2];
    const float* vec  = (const float*)d_in[3];
    const int*   f2f  = (const int*)d_in[4];
    float* out = (float*)d_out;

    char* base = (char*)d_ws;
    unsigned short* VgTh = (unsigned short*)(base + OFF_VGTH);
    unsigned short* VgTl = (unsigned short*)(base + OFF_VGTL);
    float* vnorm = (float*)(base + OFF_VN);
    float* lint  = (float*)(base + OFF_LINT);
    float* stot  = (float*)(base + OFF_STOT);

    k_prep<<<NN / 64, 256, 0, stream>>>(vec, f2f, VgTh, VgTl, vnorm, stot);  // 32 blocks
    k_main<<<GRID, TPB, 0, stream>>>(X, W, VgTh, VgTl, vnorm, lint, stot);   // 256 blocks
    k_final<<<NB / 256, 256, 0, stream>>>(lint, stot, bias, out);            // 16 blocks
}

// Round 8
// 119.532 us; speedup vs baseline: 1.1710x; 1.1710x over previous
//
#include <hip/hip_runtime.h>

// (B,N,F,K) = (4096, 2048, 64, 64)
#define NB 4096
#define NN 2048
#define NF 64
#define NK 64

#define RPB   16              // rows per block
#define TPB   1024            // 16 waves
#define NWAVE 16
#define CPW   (NN / NWAVE)    // 128 contraction cols per wave
#define KS    (CPW / 32)      // 4 MFMA K-steps per wave
#define GRID  (NB / RPB)      // 256 blocks

typedef short bf16x8 __attribute__((ext_vector_type(8)));
typedef float f32x4  __attribute__((ext_vector_type(4)));

// ws byte offsets (256B aligned)
#define OFF_VGTH 0                          // ushort [64][2048] hi
#define OFF_VGTL (OFF_VGTH + NK * NN * 2)   // ushort [64][2048] lo
#define OFF_VN   (OFF_VGTL + NK * NN * 2)   // float  [2048]
#define OFF_LINT (OFF_VN + NN * 4)          // float  [4096]
#define OFF_STOT (OFF_LINT + NB * 4)        // float  [1]

__device__ inline unsigned short bf16_rtn(float f) {
    unsigned u = __float_as_uint(f);
    return (unsigned short)((u + 0x7fffu + ((u >> 16) & 1u)) >> 16);
}

// ---------- k_prep: gather V rows, bf16 hi/lo split, store transposed [k][i]; arm stot ----------
__global__ __launch_bounds__(256) void k_prep(const float* __restrict__ vec,
                                              const int* __restrict__ f2f,
                                              unsigned short* __restrict__ VgTh,
                                              unsigned short* __restrict__ VgTl,
                                              float* __restrict__ vnorm,
                                              float* __restrict__ stot) {
    __shared__ unsigned short tH[64][72];
    __shared__ unsigned short tL[64][72];
    const int t  = threadIdx.x;
    const int i0 = blockIdx.x * 64;
    if (blockIdx.x == 0 && t == 0) *stot = 0.f;   // re-arm accumulator every launch
    {
        const int il = t >> 2;
        const int sg = (t & 3) * 16;
        const int i  = i0 + il;
        const int f  = f2f[i];
        const float* p = vec + (size_t)i * (NF * NK) + (size_t)f * NK + sg;
        float nsum = 0.f;
        #pragma unroll
        for (int j4 = 0; j4 < 4; ++j4) {
            float4 v = *reinterpret_cast<const float4*>(p + j4 * 4);
            float vv[4] = {v.x, v.y, v.z, v.w};
            #pragma unroll
            for (int e = 0; e < 4; ++e) {
                float x = vv[e];
                nsum = fmaf(x, x, nsum);
                unsigned xb = __float_as_uint(x);
                float hf = __uint_as_float(xb & 0xffff0000u);
                int k = sg + j4 * 4 + e;
                tH[il][k] = (unsigned short)(xb >> 16);
                tL[il][k] = bf16_rtn(x - hf);
            }
        }
        nsum += __shfl_xor(nsum, 1, 64);
        nsum += __shfl_xor(nsum, 2, 64);
        if ((t & 3) == 0) vnorm[i] = nsum;   // vnorm from EXACT fp32 values
    }
    __syncthreads();
    {
        const int k  = t >> 2;
        const int is = (t & 3) * 16;
        unsigned short hb[16], lb[16];
        #pragma unroll
        for (int j = 0; j < 16; ++j) { hb[j] = tH[is + j][k]; lb[j] = tL[is + j][k]; }
        unsigned short* ph = VgTh + (size_t)k * NN + i0 + is;
        unsigned short* pl = VgTl + (size_t)k * NN + i0 + is;
        *reinterpret_cast<uint4*>(ph)     = *reinterpret_cast<uint4*>(hb);
        *reinterpret_cast<uint4*>(ph + 8) = *reinterpret_cast<uint4*>(hb + 8);
        *reinterpret_cast<uint4*>(pl)     = *reinterpret_cast<uint4*>(lb);
        *reinterpret_cast<uint4*>(pl + 8) = *reinterpret_cast<uint4*>(lb + 8);
    }
}

// ---------- k_main: full-contraction MFMA + cross-wave reduce + one atomic/block ----------
// block = 16 rows x 2048 cols; wave w owns cols [128w,128w+128); 2 blocks/CU (LDS-bound).
// NOTE: plain launch_bounds — (TPB,8) capped VGPR at 32 and spilled 50 MB (R7).
__global__ __launch_bounds__(TPB) void k_main(const float* __restrict__ X,
                                              const float* __restrict__ Wg,
                                              const unsigned short* __restrict__ VgTh,
                                              const unsigned short* __restrict__ VgTl,
                                              const float* __restrict__ vn,
                                              float* __restrict__ lint,
                                              float* __restrict__ stot) {
    __shared__ float Tl[NWAVE * 1088];   // [w][row(stride 68)][lat]: 68 KB, all <=2-way
    __shared__ float linW[NWAVE * 17];
    __shared__ float ddW[NWAVE * 17];
    __shared__ float rowRes[RPB];

    const int t    = threadIdx.x;
    const int w    = t >> 6;          // wave = contraction slice
    const int lane = t & 63;
    const int m    = lane & 15;
    const int quad = lane >> 4;
    const int r0   = blockIdx.x * RPB;
    const int row  = r0 + m;
    const int cw   = w * CPW;

    const float* xp = X  + (size_t)row * NN + cw + quad * 8;
    const float* wp = Wg + cw + quad * 8;
    const float* np = vn + cw + quad * 8;
    const unsigned short* bhp = VgTh + (size_t)m * NN + cw + quad * 8;
    const unsigned short* blp = VgTl + (size_t)m * NN + cw + quad * 8;

    f32x4 acc[4];
    #pragma unroll
    for (int nt = 0; nt < 4; ++nt)
        #pragma unroll
        for (int e = 0; e < 4; ++e) acc[nt][e] = 0.f;
    float lin = 0.f, dd = 0.f;

    #pragma unroll
    for (int s = 0; s < KS; ++s) {
        float4 xa = *reinterpret_cast<const float4*>(xp + s * 32);
        float4 xb = *reinterpret_cast<const float4*>(xp + s * 32 + 4);
        float4 wa = *reinterpret_cast<const float4*>(wp + s * 32);
        float4 wb = *reinterpret_cast<const float4*>(wp + s * 32 + 4);
        float4 na = *reinterpret_cast<const float4*>(np + s * 32);
        float4 nb = *reinterpret_cast<const float4*>(np + s * 32 + 4);

        float xs8[8] = {xa.x, xa.y, xa.z, xa.w, xb.x, xb.y, xb.z, xb.w};
        float ws8[8] = {wa.x, wa.y, wa.z, wa.w, wb.x, wb.y, wb.z, wb.w};
        float ns8[8] = {na.x, na.y, na.z, na.w, nb.x, nb.y, nb.z, nb.w};

        #pragma unroll
        for (int j = 0; j < 8; ++j) {
            lin = fmaf(xs8[j], ws8[j], lin);
            dd  = fmaf(xs8[j] * xs8[j], ns8[j], dd);
        }

        bf16x8 ah, al;
        #pragma unroll
        for (int j = 0; j < 8; ++j) {
            unsigned ub = __float_as_uint(xs8[j]);
            ah[j] = (short)(ub >> 16);
            float hf = __uint_as_float(ub & 0xffff0000u);
            al[j] = (short)bf16_rtn(xs8[j] - hf);
        }

        #pragma unroll
        for (int nt = 0; nt < 4; ++nt) {
            bf16x8 bh = *reinterpret_cast<const bf16x8*>(bhp + (size_t)nt * 16 * NN + s * 32);
            bf16x8 bl = *reinterpret_cast<const bf16x8*>(blp + (size_t)nt * 16 * NN + s * 32);
            acc[nt] = __builtin_amdgcn_mfma_f32_16x16x32_bf16(ah, bh, acc[nt], 0, 0, 0);
            acc[nt] = __builtin_amdgcn_mfma_f32_16x16x32_bf16(al, bh, acc[nt], 0, 0, 0);
            acc[nt] = __builtin_amdgcn_mfma_f32_16x16x32_bf16(ah, bl, acc[nt], 0, 0, 0);
        }
    }

    // ---- stash wave-partial T tile: C-layout row=quad*4+r, col=nt*16+m ----
    #pragma unroll
    for (int nt = 0; nt < 4; ++nt)
        #pragma unroll
        for (int r = 0; r < 4; ++r)
            Tl[w * 1088 + (quad * 4 + r) * 68 + nt * 16 + m] = acc[nt][r];

    lin += __shfl_xor(lin, 16, 64); lin += __shfl_xor(lin, 32, 64);
    dd  += __shfl_xor(dd, 16, 64);  dd  += __shfl_xor(dd, 32, 64);
    if (quad == 0) { linW[w * 17 + m] = lin; ddW[w * 17 + m] = dd; }
    __syncthreads();

    // ---- per-row phase: wave w owns row w; lane = latent k ----
    {
        float ts = 0.f;
        #pragma unroll
        for (int ww = 0; ww < NWAVE; ++ww)
            ts += Tl[ww * 1088 + w * 68 + lane];
        float s2 = ts * ts;
        #pragma unroll
        for (int d = 1; d < 64; d <<= 1) s2 += __shfl_xor(s2, d, 64);
        float lw = (lane < 16) ? linW[lane * 17 + w] : 0.f;
        float dw = (lane < 16) ? ddW [lane * 17 + w] : 0.f;
        #pragma unroll
        for (int d = 1; d < 16; d <<= 1) {
            lw += __shfl_xor(lw, d, 64);
            dw += __shfl_xor(dw, d, 64);
        }
        if (lane == 0) {
            lint[r0 + w] = lw;          // per-row linear part
            rowRes[w]    = s2 - dw;     // per-row interaction partial
        }
    }
    __syncthreads();

    if (t == 0) {
        float p = 0.f;
        #pragma unroll
        for (int r = 0; r < RPB; ++r) p += rowRes[r];
        atomicAdd(stot, p);             // device-scope, no fences needed
    }
}

// ---------- k_final: broadcast ----------
__global__ __launch_bounds__(256) void k_final(const float* __restrict__ lint,
                                               const float* __restrict__ stot,
                                               const float* __restrict__ bptr,
                                               float* __restrict__ out) {
    int b = blockIdx.x * 256 + threadIdx.x;
    out[b] = lint[b] + bptr[0] + 0.5f * stot[0];
}

extern "C" void kernel_launch(void* const* d_in, const int* in_sizes, int n_in,
                              void* d_out, int out_size, void* d_ws, size_t ws_size,
                              hipStream_t stream) {
    const float* X    = (const float*)d_in[0];
    const float* W    = (const float*)d_in[1];
    const float* bias = (const float*)d_in[2];
    const float* vec  = (const float*)d_in[3];
    const int*   f2f  = (const int*)d_in[4];
    float* out = (float*)d_out;

    char* base = (char*)d_ws;
    unsigned short* VgTh = (unsigned short*)(base + OFF_VGTH);
    unsigned short* VgTl = (unsigned short*)(base + OFF_VGTL);
    float* vnorm = (float*)(base + OFF_VN);
    float* lint  = (float*)(base + OFF_LINT);
    float* stot  = (float*)(base + OFF_STOT);

    k_prep<<<NN / 64, 256, 0, stream>>>(vec, f2f, VgTh, VgTl, vnorm, stot);  // 32 blocks
    k_main<<<GRID, TPB, 0, stream>>>(X, W, VgTh, VgTl, vnorm, lint, stot);   // 256 blocks
    k_final<<<NB / 256, 256, 0, stream>>>(lint, stot, bias, out);            // 16 blocks
}

// Round 9
// 118.470 us; speedup vs baseline: 1.1815x; 1.0090x over previous
//
#include <hip/hip_runtime.h>

// (B,N,F,K) = (4096, 2048, 64, 64)
#define NB 4096
#define NN 2048
#define NF 64
#define NK 64

#define RPB   16              // rows per block
#define TPB   1024            // 16 waves
#define NWAVE 16
#define CPW   (NN / NWAVE)    // 128 contraction cols per wave
#define KS    (CPW / 32)      // 4 MFMA K-steps per wave
#define GRID  (NB / RPB)      // 256 blocks

typedef short bf16x8 __attribute__((ext_vector_type(8)));
typedef float f32x4  __attribute__((ext_vector_type(4)));

// ws byte offsets (256B aligned)
#define OFF_VGTH 0                          // ushort [64][2048] hi
#define OFF_VGTL (OFF_VGTH + NK * NN * 2)   // ushort [64][2048] lo
#define OFF_VN   (OFF_VGTL + NK * NN * 2)   // float  [2048]
#define OFF_LINT (OFF_VN + NN * 4)          // float  [4096]
#define OFF_STOT (OFF_LINT + NB * 4)        // float  [1]

__device__ inline unsigned short bf16_rtn(float f) {
    unsigned u = __float_as_uint(f);
    return (unsigned short)((u + 0x7fffu + ((u >> 16) & 1u)) >> 16);
}

// ---------- k_prep: gather V rows, bf16 hi/lo split, store transposed [k][i]; arm stot ----------
__global__ __launch_bounds__(256) void k_prep(const float* __restrict__ vec,
                                              const int* __restrict__ f2f,
                                              unsigned short* __restrict__ VgTh,
                                              unsigned short* __restrict__ VgTl,
                                              float* __restrict__ vnorm,
                                              float* __restrict__ stot) {
    __shared__ unsigned short tH[64][72];
    __shared__ unsigned short tL[64][72];
    const int t  = threadIdx.x;
    const int i0 = blockIdx.x * 64;
    if (blockIdx.x == 0 && t == 0) *stot = 0.f;   // re-arm accumulator every launch
    {
        const int il = t >> 2;
        const int sg = (t & 3) * 16;
        const int i  = i0 + il;
        const int f  = f2f[i];
        const float* p = vec + (size_t)i * (NF * NK) + (size_t)f * NK + sg;
        float nsum = 0.f;
        #pragma unroll
        for (int j4 = 0; j4 < 4; ++j4) {
            float4 v = *reinterpret_cast<const float4*>(p + j4 * 4);
            float vv[4] = {v.x, v.y, v.z, v.w};
            #pragma unroll
            for (int e = 0; e < 4; ++e) {
                float x = vv[e];
                nsum = fmaf(x, x, nsum);
                unsigned xb = __float_as_uint(x);
                float hf = __uint_as_float(xb & 0xffff0000u);
                int k = sg + j4 * 4 + e;
                tH[il][k] = (unsigned short)(xb >> 16);
                tL[il][k] = bf16_rtn(x - hf);
            }
        }
        nsum += __shfl_xor(nsum, 1, 64);
        nsum += __shfl_xor(nsum, 2, 64);
        if ((t & 3) == 0) vnorm[i] = nsum;   // vnorm from EXACT fp32 values
    }
    __syncthreads();
    {
        const int k  = t >> 2;
        const int is = (t & 3) * 16;
        unsigned short hb[16], lb[16];
        #pragma unroll
        for (int j = 0; j < 16; ++j) { hb[j] = tH[is + j][k]; lb[j] = tL[is + j][k]; }
        unsigned short* ph = VgTh + (size_t)k * NN + i0 + is;
        unsigned short* pl = VgTl + (size_t)k * NN + i0 + is;
        *reinterpret_cast<uint4*>(ph)     = *reinterpret_cast<uint4*>(hb);
        *reinterpret_cast<uint4*>(ph + 8) = *reinterpret_cast<uint4*>(hb + 8);
        *reinterpret_cast<uint4*>(pl)     = *reinterpret_cast<uint4*>(lb);
        *reinterpret_cast<uint4*>(pl + 8) = *reinterpret_cast<uint4*>(lb + 8);
    }
}

// ---------- k_main: full-contraction MFMA + cross-wave reduce + one atomic/block ----------
// block = 16 rows x 2048 cols; wave w owns cols [128w,128w+128).
// __launch_bounds__(1024,4): VGPR cap 128 (1 block/CU, 4 waves/SIMD) so the compiler
// can hoist all 4 unrolled steps' loads — at the default (44 VGPR, 8 waves/SIMD) the
// loop serializes on vmcnt(0) per step. (1024,8) spilled 50 MB (R7); plain = 44 reg (R5).
__global__ __launch_bounds__(TPB, 4) void k_main(const float* __restrict__ X,
                                                 const float* __restrict__ Wg,
                                                 const unsigned short* __restrict__ VgTh,
                                                 const unsigned short* __restrict__ VgTl,
                                                 const float* __restrict__ vn,
                                                 float* __restrict__ lint,
                                                 float* __restrict__ stot) {
    __shared__ float Tl[NWAVE * 1088];   // [w][row(stride 68)][lat]: 68 KB, all <=2-way
    __shared__ float linW[NWAVE * 17];
    __shared__ float ddW[NWAVE * 17];
    __shared__ float rowRes[RPB];

    const int t    = threadIdx.x;
    const int w    = t >> 6;          // wave = contraction slice
    const int lane = t & 63;
    const int m    = lane & 15;
    const int quad = lane >> 4;
    const int r0   = blockIdx.x * RPB;
    const int row  = r0 + m;
    const int cw   = w * CPW;

    const float* xp = X  + (size_t)row * NN + cw + quad * 8;
    const float* wp = Wg + cw + quad * 8;
    const float* np = vn + cw + quad * 8;
    const unsigned short* bhp = VgTh + (size_t)m * NN + cw + quad * 8;
    const unsigned short* blp = VgTl + (size_t)m * NN + cw + quad * 8;

    f32x4 acc[4];
    #pragma unroll
    for (int nt = 0; nt < 4; ++nt)
        #pragma unroll
        for (int e = 0; e < 4; ++e) acc[nt][e] = 0.f;
    float lin = 0.f, dd = 0.f;

    #pragma unroll
    for (int s = 0; s < KS; ++s) {
        float4 xa = *reinterpret_cast<const float4*>(xp + s * 32);
        float4 xb = *reinterpret_cast<const float4*>(xp + s * 32 + 4);
        float4 wa = *reinterpret_cast<const float4*>(wp + s * 32);
        float4 wb = *reinterpret_cast<const float4*>(wp + s * 32 + 4);
        float4 na = *reinterpret_cast<const float4*>(np + s * 32);
        float4 nb = *reinterpret_cast<const float4*>(np + s * 32 + 4);

        float xs8[8] = {xa.x, xa.y, xa.z, xa.w, xb.x, xb.y, xb.z, xb.w};
        float ws8[8] = {wa.x, wa.y, wa.z, wa.w, wb.x, wb.y, wb.z, wb.w};
        float ns8[8] = {na.x, na.y, na.z, na.w, nb.x, nb.y, nb.z, nb.w};

        #pragma unroll
        for (int j = 0; j < 8; ++j) {
            lin = fmaf(xs8[j], ws8[j], lin);
            dd  = fmaf(xs8[j] * xs8[j], ns8[j], dd);
        }

        bf16x8 ah, al;
        #pragma unroll
        for (int j = 0; j < 8; ++j) {
            unsigned ub = __float_as_uint(xs8[j]);
            ah[j] = (short)(ub >> 16);
            float hf = __uint_as_float(ub & 0xffff0000u);
            al[j] = (short)bf16_rtn(xs8[j] - hf);
        }

        #pragma unroll
        for (int nt = 0; nt < 4; ++nt) {
            bf16x8 bh = *reinterpret_cast<const bf16x8*>(bhp + (size_t)nt * 16 * NN + s * 32);
            bf16x8 bl = *reinterpret_cast<const bf16x8*>(blp + (size_t)nt * 16 * NN + s * 32);
            acc[nt] = __builtin_amdgcn_mfma_f32_16x16x32_bf16(ah, bh, acc[nt], 0, 0, 0);
            acc[nt] = __builtin_amdgcn_mfma_f32_16x16x32_bf16(al, bh, acc[nt], 0, 0, 0);
            acc[nt] = __builtin_amdgcn_mfma_f32_16x16x32_bf16(ah, bl, acc[nt], 0, 0, 0);
        }
    }

    // ---- stash wave-partial T tile: C-layout row=quad*4+r, col=nt*16+m ----
    #pragma unroll
    for (int nt = 0; nt < 4; ++nt)
        #pragma unroll
        for (int r = 0; r < 4; ++r)
            Tl[w * 1088 + (quad * 4 + r) * 68 + nt * 16 + m] = acc[nt][r];

    lin += __shfl_xor(lin, 16, 64); lin += __shfl_xor(lin, 32, 64);
    dd  += __shfl_xor(dd, 16, 64);  dd  += __shfl_xor(dd, 32, 64);
    if (quad == 0) { linW[w * 17 + m] = lin; ddW[w * 17 + m] = dd; }
    __syncthreads();

    // ---- per-row phase: wave w owns row w; lane = latent k ----
    {
        float ts = 0.f;
        #pragma unroll
        for (int ww = 0; ww < NWAVE; ++ww)
            ts += Tl[ww * 1088 + w * 68 + lane];
        float s2 = ts * ts;
        #pragma unroll
        for (int d = 1; d < 64; d <<= 1) s2 += __shfl_xor(s2, d, 64);
        float lw = (lane < 16) ? linW[lane * 17 + w] : 0.f;
        float dw = (lane < 16) ? ddW [lane * 17 + w] : 0.f;
        #pragma unroll
        for (int d = 1; d < 16; d <<= 1) {
            lw += __shfl_xor(lw, d, 64);
            dw += __shfl_xor(dw, d, 64);
        }
        if (lane == 0) {
            lint[r0 + w] = lw;          // per-row linear part
            rowRes[w]    = s2 - dw;     // per-row interaction partial
        }
    }
    __syncthreads();

    if (t == 0) {
        float p = 0.f;
        #pragma unroll
        for (int r = 0; r < RPB; ++r) p += rowRes[r];
        atomicAdd(stot, p);             // device-scope, no fences needed
    }
}

// ---------- k_final: broadcast ----------
__global__ __launch_bounds__(256) void k_final(const float* __restrict__ lint,
                                               const float* __restrict__ stot,
                                               const float* __restrict__ bptr,
                                               float* __restrict__ out) {
    int b = blockIdx.x * 256 + threadIdx.x;
    out[b] = lint[b] + bptr[0] + 0.5f * stot[0];
}

extern "C" void kernel_launch(void* const* d_in, const int* in_sizes, int n_in,
                              void* d_out, int out_size, void* d_ws, size_t ws_size,
                              hipStream_t stream) {
    const float* X    = (const float*)d_in[0];
    const float* W    = (const float*)d_in[1];
    const float* bias = (const float*)d_in[2];
    const float* vec  = (const float*)d_in[3];
    const int*   f2f  = (const int*)d_in[4];
    float* out = (float*)d_out;

    char* base = (char*)d_ws;
    unsigned short* VgTh = (unsigned short*)(base + OFF_VGTH);
    unsigned short* VgTl = (unsigned short*)(base + OFF_VGTL);
    float* vnorm = (float*)(base + OFF_VN);
    float* lint  = (float*)(base + OFF_LINT);
    float* stot  = (float*)(base + OFF_STOT);

    k_prep<<<NN / 64, 256, 0, stream>>>(vec, f2f, VgTh, VgTl, vnorm, stot);  // 32 blocks
    k_main<<<GRID, TPB, 0, stream>>>(X, W, VgTh, VgTl, vnorm, lint, stot);   // 256 blocks
    k_final<<<NB / 256, 256, 0, stream>>>(lint, stot, bias, out);            // 16 blocks
}

// Round 10
// 111.644 us; speedup vs baseline: 1.2538x; 1.0611x over previous
//
#include <hip/hip_runtime.h>

// (B,N,F,K) = (4096, 2048, 64, 64)
#define NB 4096
#define NN 2048
#define NF 64
#define NK 64

#define RPB   16              // rows per block
#define TPB   1024            // 16 waves
#define NWAVE 16
#define CPW   (NN / NWAVE)    // 128 contraction cols per wave
#define KS    (CPW / 32)      // 4 MFMA K-steps per wave
#define GRID  (NB / RPB)      // 256 blocks

typedef short bf16x8 __attribute__((ext_vector_type(8)));
typedef float f32x4  __attribute__((ext_vector_type(4)));

// ws byte offsets (256B aligned)
// VgF: fragment-major B, ushort[64 S][8 region][512]:
//   region = nt*2 + (0=hi,1=lo); within region, lane(m,q) data at ((m*4)+q)*8..+8,
//   element j of that chunk = bf16(V[i = S*32 + q*8 + j][latent = nt*16+m])
#define OFF_VGF  0                          // 512 KB
#define OFF_VN   (OFF_VGF + 64 * 8 * 512 * 2)
#define OFF_LINT (OFF_VN + NN * 4)          // float [4096]
#define OFF_STOT (OFF_LINT + NB * 4)        // float [1]

__device__ inline unsigned short bf16_rtn(float f) {
    unsigned u = __float_as_uint(f);
    return (unsigned short)((u + 0x7fffu + ((u >> 16) & 1u)) >> 16);
}

// ---------- k_prep: gather V rows, bf16 hi/lo split, store FRAGMENT-MAJOR; arm stot ----------
__global__ __launch_bounds__(256) void k_prep(const float* __restrict__ vec,
                                              const int* __restrict__ f2f,
                                              unsigned short* __restrict__ VgF,
                                              float* __restrict__ vnorm,
                                              float* __restrict__ stot) {
    __shared__ unsigned short tH[64][72];   // [local contraction i'][latent k]
    __shared__ unsigned short tL[64][72];
    const int t  = threadIdx.x;
    const int i0 = blockIdx.x * 64;         // 64 contraction cols = 2 K-steps
    if (blockIdx.x == 0 && t == 0) *stot = 0.f;   // re-arm accumulator every launch
    {
        const int il = t >> 2;
        const int sg = (t & 3) * 16;
        const int i  = i0 + il;
        const int f  = f2f[i];
        const float* p = vec + (size_t)i * (NF * NK) + (size_t)f * NK + sg;
        float nsum = 0.f;
        #pragma unroll
        for (int j4 = 0; j4 < 4; ++j4) {
            float4 v = *reinterpret_cast<const float4*>(p + j4 * 4);
            float vv[4] = {v.x, v.y, v.z, v.w};
            #pragma unroll
            for (int e = 0; e < 4; ++e) {
                float x = vv[e];
                nsum = fmaf(x, x, nsum);
                unsigned xb = __float_as_uint(x);
                float hf = __uint_as_float(xb & 0xffff0000u);
                int k = sg + j4 * 4 + e;
                tH[il][k] = (unsigned short)(xb >> 16);
                tL[il][k] = bf16_rtn(x - hf);
            }
        }
        nsum += __shfl_xor(nsum, 1, 64);
        nsum += __shfl_xor(nsum, 2, 64);
        if ((t & 3) == 0) vnorm[i] = nsum;   // vnorm from EXACT fp32 values
    }
    __syncthreads();
    // phase 2: thread t = (latent r = t>>2, seg = t&3 covering i' = 16*seg..16*seg+15)
    {
        const int r   = t >> 2;
        const int seg = t & 3;
        const int S   = blockIdx.x * 2 + (seg >> 1);   // global K-step
        const int q1  = (seg & 1) * 2;
        unsigned short hb[16], lb[16];
        #pragma unroll
        for (int u = 0; u < 16; ++u) {
            hb[u] = tH[seg * 16 + u][r];
            lb[u] = tL[seg * 16 + u][r];
        }
        // hi region = S*8 + (r>>4)*2; lo at +512 elements
        unsigned short* d = VgF + ((size_t)S * 8 + (r >> 4) * 2) * 512
                                + ((r & 15) * 4 + q1) * 8;
        *reinterpret_cast<uint4*>(d)            = *reinterpret_cast<uint4*>(hb);
        *reinterpret_cast<uint4*>(d + 8)        = *reinterpret_cast<uint4*>(hb + 8);
        *reinterpret_cast<uint4*>(d + 512)      = *reinterpret_cast<uint4*>(lb);
        *reinterpret_cast<uint4*>(d + 512 + 8)  = *reinterpret_cast<uint4*>(lb + 8);
    }
}

// ---------- k_main: full-contraction MFMA + cross-wave reduce + one atomic/block ----------
// block = 16 rows x 2048 cols; wave w owns cols [128w,128w+128).
// B loads are single-segment 1KB (fragment-major VgF) with immediate offsets.
__global__ __launch_bounds__(TPB, 4) void k_main(const float* __restrict__ X,
                                                 const float* __restrict__ Wg,
                                                 const unsigned short* __restrict__ VgF,
                                                 const float* __restrict__ vn,
                                                 float* __restrict__ lint,
                                                 float* __restrict__ stot) {
    __shared__ float Tl[NWAVE * 1088];   // [w][row(stride 68)][lat]: 68 KB, all <=2-way
    __shared__ float linW[NWAVE * 17];
    __shared__ float ddW[NWAVE * 17];
    __shared__ float rowRes[RPB];

    const int t    = threadIdx.x;
    const int w    = t >> 6;          // wave = contraction slice
    const int lane = t & 63;
    const int m    = lane & 15;
    const int quad = lane >> 4;
    const int r0   = blockIdx.x * RPB;
    const int row  = r0 + m;
    const int cw   = w * CPW;

    const float* xp = X  + (size_t)row * NN + cw + quad * 8;
    const float* wp = Wg + cw + quad * 8;
    const float* np = vn + cw + quad * 8;
    // fragment-major B: per-lane 16B chunk at (4m+q)*8 elements within each 512-el region
    const unsigned short* bp = VgF + (size_t)(w * 4) * 4096 + (m * 4 + quad) * 8;

    f32x4 acc[4];
    #pragma unroll
    for (int nt = 0; nt < 4; ++nt)
        #pragma unroll
        for (int e = 0; e < 4; ++e) acc[nt][e] = 0.f;
    float lin = 0.f, dd = 0.f;

    #pragma unroll
    for (int s = 0; s < KS; ++s) {
        float4 xa = *reinterpret_cast<const float4*>(xp + s * 32);
        float4 xb = *reinterpret_cast<const float4*>(xp + s * 32 + 4);
        float4 wa = *reinterpret_cast<const float4*>(wp + s * 32);
        float4 wb = *reinterpret_cast<const float4*>(wp + s * 32 + 4);
        float4 na = *reinterpret_cast<const float4*>(np + s * 32);
        float4 nb = *reinterpret_cast<const float4*>(np + s * 32 + 4);

        float xs8[8] = {xa.x, xa.y, xa.z, xa.w, xb.x, xb.y, xb.z, xb.w};
        float ws8[8] = {wa.x, wa.y, wa.z, wa.w, wb.x, wb.y, wb.z, wb.w};
        float ns8[8] = {na.x, na.y, na.z, na.w, nb.x, nb.y, nb.z, nb.w};

        #pragma unroll
        for (int j = 0; j < 8; ++j) {
            lin = fmaf(xs8[j], ws8[j], lin);
            dd  = fmaf(xs8[j] * xs8[j], ns8[j], dd);
        }

        bf16x8 ah, al;
        #pragma unroll
        for (int j = 0; j < 8; ++j) {
            unsigned ub = __float_as_uint(xs8[j]);
            ah[j] = (short)(ub >> 16);
            float hf = __uint_as_float(ub & 0xffff0000u);
            al[j] = (short)bf16_rtn(xs8[j] - hf);
        }

        const unsigned short* bs = bp + (size_t)s * 4096;   // 8 regions of 512 el per step
        #pragma unroll
        for (int nt = 0; nt < 4; ++nt) {
            bf16x8 bh = *reinterpret_cast<const bf16x8*>(bs + nt * 1024);
            bf16x8 bl = *reinterpret_cast<const bf16x8*>(bs + nt * 1024 + 512);
            acc[nt] = __builtin_amdgcn_mfma_f32_16x16x32_bf16(ah, bh, acc[nt], 0, 0, 0);
            acc[nt] = __builtin_amdgcn_mfma_f32_16x16x32_bf16(al, bh, acc[nt], 0, 0, 0);
            acc[nt] = __builtin_amdgcn_mfma_f32_16x16x32_bf16(ah, bl, acc[nt], 0, 0, 0);
        }
    }

    // ---- stash wave-partial T tile: C-layout row=quad*4+r, col=nt*16+m ----
    #pragma unroll
    for (int nt = 0; nt < 4; ++nt)
        #pragma unroll
        for (int r = 0; r < 4; ++r)
            Tl[w * 1088 + (quad * 4 + r) * 68 + nt * 16 + m] = acc[nt][r];

    lin += __shfl_xor(lin, 16, 64); lin += __shfl_xor(lin, 32, 64);
    dd  += __shfl_xor(dd, 16, 64);  dd  += __shfl_xor(dd, 32, 64);
    if (quad == 0) { linW[w * 17 + m] = lin; ddW[w * 17 + m] = dd; }
    __syncthreads();

    // ---- per-row phase: wave w owns row w; lane = latent k ----
    {
        float ts = 0.f;
        #pragma unroll
        for (int ww = 0; ww < NWAVE; ++ww)
            ts += Tl[ww * 1088 + w * 68 + lane];
        float s2 = ts * ts;
        #pragma unroll
        for (int d = 1; d < 64; d <<= 1) s2 += __shfl_xor(s2, d, 64);
        float lw = (lane < 16) ? linW[lane * 17 + w] : 0.f;
        float dw = (lane < 16) ? ddW [lane * 17 + w] : 0.f;
        #pragma unroll
        for (int d = 1; d < 16; d <<= 1) {
            lw += __shfl_xor(lw, d, 64);
            dw += __shfl_xor(dw, d, 64);
        }
        if (lane == 0) {
            lint[r0 + w] = lw;          // per-row linear part
            rowRes[w]    = s2 - dw;     // per-row interaction partial
        }
    }
    __syncthreads();

    if (t == 0) {
        float p = 0.f;
        #pragma unroll
        for (int r = 0; r < RPB; ++r) p += rowRes[r];
        atomicAdd(stot, p);             // device-scope, no fences needed
    }
}

// ---------- k_final: broadcast ----------
__global__ __launch_bounds__(256) void k_final(const float* __restrict__ lint,
                                               const float* __restrict__ stot,
                                               const float* __restrict__ bptr,
                                               float* __restrict__ out) {
    int b = blockIdx.x * 256 + threadIdx.x;
    out[b] = lint[b] + bptr[0] + 0.5f * stot[0];
}

extern "C" void kernel_launch(void* const* d_in, const int* in_sizes, int n_in,
                              void* d_out, int out_size, void* d_ws, size_t ws_size,
                              hipStream_t stream) {
    const float* X    = (const float*)d_in[0];
    const float* W    = (const float*)d_in[1];
    const float* bias = (const float*)d_in[2];
    const float* vec  = (const float*)d_in[3];
    const int*   f2f  = (const int*)d_in[4];
    float* out = (float*)d_out;

    char* base = (char*)d_ws;
    unsigned short* VgF = (unsigned short*)(base + OFF_VGF);
    float* vnorm = (float*)(base + OFF_VN);
    float* lint  = (float*)(base + OFF_LINT);
    float* stot  = (float*)(base + OFF_STOT);

    k_prep<<<NN / 64, 256, 0, stream>>>(vec, f2f, VgF, vnorm, stot);       // 32 blocks
    k_main<<<GRID, TPB, 0, stream>>>(X, W, VgF, vnorm, lint, stot);        // 256 blocks
    k_final<<<NB / 256, 256, 0, stream>>>(lint, stot, bias, out);          // 16 blocks
}

// Round 11
// 111.056 us; speedup vs baseline: 1.2604x; 1.0053x over previous
//
#include <hip/hip_runtime.h>

// (B,N,F,K) = (4096, 2048, 64, 64)
#define NB 4096
#define NN 2048
#define NF 64
#define NK 64

#define RPB   16              // rows per block
#define TPB   1024            // 16 waves
#define NWAVE 16
#define CPW   (NN / NWAVE)    // 128 contraction cols per wave
#define KS    (CPW / 32)      // 4 MFMA K-steps per wave
#define GRID  (NB / RPB)      // 256 blocks

typedef short bf16x8 __attribute__((ext_vector_type(8)));
typedef float f32x4  __attribute__((ext_vector_type(4)));

// ws byte offsets (256B aligned)
// VgF: fragment-major B, ushort[64 S][8 region][512], region = nt*2 + (0=hi,1=lo).
// Chunk (m,q) at ((m*4)+q)*8; element j = bf16(V[i = S*32 + PI(q,j)][latent nt*16+m])
// where PI(q,j) = (j<4 ? q*4+j : 16 + q*4 + (j-4))  — the "full-line" contraction
// permutation: X's xa load then covers cols 0-15 (one full 64B line per row), xb cols 16-31.
#define OFF_VGF  0                          // 512 KB
#define OFF_VN   (OFF_VGF + 64 * 8 * 512 * 2)
#define OFF_LINT (OFF_VN + NN * 4)          // float [4096]
#define OFF_STOT (OFF_LINT + NB * 4)        // float [1]

__device__ inline unsigned short bf16_rtn(float f) {
    unsigned u = __float_as_uint(f);
    return (unsigned short)((u + 0x7fffu + ((u >> 16) & 1u)) >> 16);
}

// ---------- k_prep: gather V rows, bf16 hi/lo split, store FRAGMENT-MAJOR (PI order) ----------
__global__ __launch_bounds__(256) void k_prep(const float* __restrict__ vec,
                                              const int* __restrict__ f2f,
                                              unsigned short* __restrict__ VgF,
                                              float* __restrict__ vnorm,
                                              float* __restrict__ stot) {
    __shared__ unsigned short tH[64][72];   // [local contraction i'][latent]
    __shared__ unsigned short tL[64][72];
    const int t  = threadIdx.x;
    const int i0 = blockIdx.x * 64;         // 64 contraction cols = 2 K-steps
    if (blockIdx.x == 0 && t == 0) *stot = 0.f;   // re-arm accumulator every launch
    {
        const int il = t >> 2;
        const int sg = (t & 3) * 16;
        const int i  = i0 + il;
        const int f  = f2f[i];
        const float* p = vec + (size_t)i * (NF * NK) + (size_t)f * NK + sg;
        float nsum = 0.f;
        #pragma unroll
        for (int j4 = 0; j4 < 4; ++j4) {
            float4 v = *reinterpret_cast<const float4*>(p + j4 * 4);
            float vv[4] = {v.x, v.y, v.z, v.w};
            #pragma unroll
            for (int e = 0; e < 4; ++e) {
                float x = vv[e];
                nsum = fmaf(x, x, nsum);
                unsigned xb = __float_as_uint(x);
                float hf = __uint_as_float(xb & 0xffff0000u);
                int k = sg + j4 * 4 + e;
                tH[il][k] = (unsigned short)(xb >> 16);
                tL[il][k] = bf16_rtn(x - hf);
            }
        }
        nsum += __shfl_xor(nsum, 1, 64);
        nsum += __shfl_xor(nsum, 2, 64);
        if ((t & 3) == 0) vnorm[i] = nsum;   // vnorm from EXACT fp32 values
    }
    __syncthreads();
    // phase 2: thread t = (latent r = t>>2, quad q = t&3): writes chunk (r&15, q)
    // of both K-steps of this block, hi and lo, in PI order.
    {
        const int r = t >> 2;
        const int q = t & 3;
        #pragma unroll
        for (int step = 0; step < 2; ++step) {
            const int S  = blockIdx.x * 2 + step;
            const int bi = step * 32;
            unsigned short hb[8], lb[8];
            #pragma unroll
            for (int j = 0; j < 8; ++j) {
                int idx = (j < 4) ? (q * 4 + j) : (12 + q * 4 + j);  // PI(q,j)
                hb[j] = tH[bi + idx][r];
                lb[j] = tL[bi + idx][r];
            }
            unsigned short* d = VgF + ((size_t)S * 8 + (r >> 4) * 2) * 512
                                    + ((r & 15) * 4 + q) * 8;
            *reinterpret_cast<uint4*>(d)       = *reinterpret_cast<uint4*>(hb);
            *reinterpret_cast<uint4*>(d + 512) = *reinterpret_cast<uint4*>(lb);
        }
    }
}

// ---------- k_main: full-contraction MFMA + cross-wave reduce + one atomic/block ----------
// block = 16 rows x 2048 cols; wave w owns cols [128w,128w+128).
// X/W/vn loads are full-line (PI permutation); B loads single-segment 1KB (VgF).
__global__ __launch_bounds__(TPB, 4) void k_main(const float* __restrict__ X,
                                                 const float* __restrict__ Wg,
                                                 const unsigned short* __restrict__ VgF,
                                                 const float* __restrict__ vn,
                                                 float* __restrict__ lint,
                                                 float* __restrict__ stot) {
    __shared__ float Tl[NWAVE * 1088];   // [w][row(stride 68)][lat]: 68 KB, all <=2-way
    __shared__ float linW[NWAVE * 17];
    __shared__ float ddW[NWAVE * 17];
    __shared__ float rowRes[RPB];

    const int t    = threadIdx.x;
    const int w    = t >> 6;          // wave = contraction slice
    const int lane = t & 63;
    const int m    = lane & 15;
    const int quad = lane >> 4;
    const int r0   = blockIdx.x * RPB;
    const int row  = r0 + m;
    const int cw   = w * CPW;

    // PI layout: xa covers cols 0-15 of the step (full line 0), xb cols 16-31 (line 1);
    // lane(m,q) takes the q*4..q*4+3 slice of each line.
    const float* xp = X  + (size_t)row * NN + cw + quad * 4;
    const float* wp = Wg + cw + quad * 4;
    const float* np = vn + cw + quad * 4;
    const unsigned short* bp = VgF + (size_t)(w * 4) * 4096 + (m * 4 + quad) * 8;

    f32x4 acc[4];
    #pragma unroll
    for (int nt = 0; nt < 4; ++nt)
        #pragma unroll
        for (int e = 0; e < 4; ++e) acc[nt][e] = 0.f;
    float lin = 0.f, dd = 0.f;

    #pragma unroll
    for (int s = 0; s < KS; ++s) {
        float4 xa = *reinterpret_cast<const float4*>(xp + s * 32);
        float4 xb = *reinterpret_cast<const float4*>(xp + s * 32 + 16);
        float4 wa = *reinterpret_cast<const float4*>(wp + s * 32);
        float4 wb = *reinterpret_cast<const float4*>(wp + s * 32 + 16);
        float4 na = *reinterpret_cast<const float4*>(np + s * 32);
        float4 nb = *reinterpret_cast<const float4*>(np + s * 32 + 16);

        float xs8[8] = {xa.x, xa.y, xa.z, xa.w, xb.x, xb.y, xb.z, xb.w};
        float ws8[8] = {wa.x, wa.y, wa.z, wa.w, wb.x, wb.y, wb.z, wb.w};
        float ns8[8] = {na.x, na.y, na.z, na.w, nb.x, nb.y, nb.z, nb.w};

        #pragma unroll
        for (int j = 0; j < 8; ++j) {
            lin = fmaf(xs8[j], ws8[j], lin);
            dd  = fmaf(xs8[j] * xs8[j], ns8[j], dd);
        }

        bf16x8 ah, al;
        #pragma unroll
        for (int j = 0; j < 8; ++j) {
            unsigned ub = __float_as_uint(xs8[j]);
            ah[j] = (short)(ub >> 16);
            float hf = __uint_as_float(ub & 0xffff0000u);
            al[j] = (short)bf16_rtn(xs8[j] - hf);
        }

        const unsigned short* bs = bp + (size_t)s * 4096;   // 8 regions of 512 el per step
        #pragma unroll
        for (int nt = 0; nt < 4; ++nt) {
            bf16x8 bh = *reinterpret_cast<const bf16x8*>(bs + nt * 1024);
            bf16x8 bl = *reinterpret_cast<const bf16x8*>(bs + nt * 1024 + 512);
            acc[nt] = __builtin_amdgcn_mfma_f32_16x16x32_bf16(ah, bh, acc[nt], 0, 0, 0);
            acc[nt] = __builtin_amdgcn_mfma_f32_16x16x32_bf16(al, bh, acc[nt], 0, 0, 0);
            acc[nt] = __builtin_amdgcn_mfma_f32_16x16x32_bf16(ah, bl, acc[nt], 0, 0, 0);
        }
    }

    // ---- stash wave-partial T tile: C-layout row=quad*4+r, col=nt*16+m ----
    #pragma unroll
    for (int nt = 0; nt < 4; ++nt)
        #pragma unroll
        for (int r = 0; r < 4; ++r)
            Tl[w * 1088 + (quad * 4 + r) * 68 + nt * 16 + m] = acc[nt][r];

    lin += __shfl_xor(lin, 16, 64); lin += __shfl_xor(lin, 32, 64);
    dd  += __shfl_xor(dd, 16, 64);  dd  += __shfl_xor(dd, 32, 64);
    if (quad == 0) { linW[w * 17 + m] = lin; ddW[w * 17 + m] = dd; }
    __syncthreads();

    // ---- per-row phase: wave w owns row w; lane = latent k ----
    {
        float ts = 0.f;
        #pragma unroll
        for (int ww = 0; ww < NWAVE; ++ww)
            ts += Tl[ww * 1088 + w * 68 + lane];
        float s2 = ts * ts;
        #pragma unroll
        for (int d = 1; d < 64; d <<= 1) s2 += __shfl_xor(s2, d, 64);
        float lw = (lane < 16) ? linW[lane * 17 + w] : 0.f;
        float dw = (lane < 16) ? ddW [lane * 17 + w] : 0.f;
        #pragma unroll
        for (int d = 1; d < 16; d <<= 1) {
            lw += __shfl_xor(lw, d, 64);
            dw += __shfl_xor(dw, d, 64);
        }
        if (lane == 0) {
            lint[r0 + w] = lw;          // per-row linear part
            rowRes[w]    = s2 - dw;     // per-row interaction partial
        }
    }
    __syncthreads();

    if (t == 0) {
        float p = 0.f;
        #pragma unroll
        for (int r = 0; r < RPB; ++r) p += rowRes[r];
        atomicAdd(stot, p);             // device-scope, no fences needed
    }
}

// ---------- k_final: broadcast ----------
__global__ __launch_bounds__(256) void k_final(const float* __restrict__ lint,
                                               const float* __restrict__ stot,
                                               const float* __restrict__ bptr,
                                               float* __restrict__ out) {
    int b = blockIdx.x * 256 + threadIdx.x;
    out[b] = lint[b] + bptr[0] + 0.5f * stot[0];
}

extern "C" void kernel_launch(void* const* d_in, const int* in_sizes, int n_in,
                              void* d_out, int out_size, void* d_ws, size_t ws_size,
                              hipStream_t stream) {
    const float* X    = (const float*)d_in[0];
    const float* W    = (const float*)d_in[1];
    const float* bias = (const float*)d_in[2];
    const float* vec  = (const float*)d_in[3];
    const int*   f2f  = (const int*)d_in[4];
    float* out = (float*)d_out;

    char* base = (char*)d_ws;
    unsigned short* VgF = (unsigned short*)(base + OFF_VGF);
    float* vnorm = (float*)(base + OFF_VN);
    float* lint  = (float*)(base + OFF_LINT);
    float* stot  = (float*)(base + OFF_STOT);

    k_prep<<<NN / 64, 256, 0, stream>>>(vec, f2f, VgF, vnorm, stot);       // 32 blocks
    k_main<<<GRID, TPB, 0, stream>>>(X, W, VgF, vnorm, lint, stot);        // 256 blocks
    k_final<<<NB / 256, 256, 0, stream>>>(lint, stot, bias, out);          // 16 blocks
}